// Round 9
// baseline (169.949 us; speedup 1.0000x reference)
//
#include <hip/hip_runtime.h>

// GCN on 100K nodes / 1.6M edges; output depends only on node_index's 3-hop
// in-neighborhood. v10 = v9 + L1-resident bitmap membership tests.
// Post-mortem ledger:
//  - v4: grid.sync ~120us/sync. v7: ticket barrier ~15us/boundary. No device
//    sync ever; dispatch chain depth (7) is structural.
//  - v6(9 disp) vs v9(7 disp): ~2us/dispatch only => remaining ~125us is
//    real scan work, dominated by 1.6M scattered 4B probes into 400KB
//    tables (1 random 64B L2 line each, ~102MB L2 traffic per scan).
//  - v10: membership tests via 12.5KB bitmaps (fit in 32KB L1). Full tables
//    touched only on hits (~280/4.6K/80K). Zero region shrinks to 38KB;
//    deg/slot1/rc* zeroed grid-stride inside scanF1.
// Stages (7): memset(38KB) -> scanF1 -> scanF2 -> scanS -> scanDeg -> l1 ->
// l2tail.
//   F1 = in(n0) u {n0}   (~17)   -> bm2 bitmap + node2[] (row = index)
//   F2 = in(F1) u F1     (~290)  -> bm1 bitmap + slot1[]/node1[] -> h1c
//   S  = F2 u in(F2)     (~5K)   -> bmN bitmap: degree targets
// slot1: 0=empty, -1=claiming, v>0 = row v-1 (zeroed in scanF1).

#define HID  64
#define CAP1 2048   // compact rows for F2 (layer-1 outputs)
#define CAP2 512    // compact rows for F1 (layer-2 outputs)
#define RB1  128    // per-row in-edge bucket depth, layer 1
#define RB2  128    // per-row in-edge bucket depth, layer 2
#define CL3  2048   // layer-3 edge list capacity
#define VE   8      // edges per thread in scans
#define TPB  256
#define TT   1024   // threads in fused l2tail (16 waves)
#define NW   16
#define BMW  3200   // bitmap words (100K bits, padded)

__device__ __forceinline__ int bmTest(const unsigned* bm, int i) {
  return (bm[i >> 5] >> (i & 31)) & 1u;
}
__device__ __forceinline__ int bmSet(unsigned* bm, int i) {  // ret 1 if new
  unsigned old = atomicOr(&bm[i >> 5], 1u << (i & 31));
  return !((old >> (i & 31)) & 1u);
}

// wave-level dtype probe: high dwords of first 64 entries all zero -> int64
__device__ __forceinline__ int detect64(const void* ei) {
  const unsigned* e32 = (const unsigned*)ei;
  int lane = threadIdx.x & 63;
  bool z = (e32[2 * lane + 1] == 0u);
  return (__ballot(z) == ~0ull) ? 1 : 0;
}

__device__ __forceinline__ int ld_src(const void* ei, int is64, long long e) {
  return is64 ? (int)((const unsigned*)ei)[e << 1] : ((const int*)ei)[e];
}

// load up to VE dst values from the raw edge index (scanF1 only)
__device__ __forceinline__ int load_dsts(const void* ei, long long E, long long base,
                                         int is64, int d[VE]) {
  int n = (int)((E - base) < VE ? (E - base) : VE);
  if (is64) {
    const unsigned long long* p = (const unsigned long long*)ei + E + base;
    if (n == VE && (((E + base) & 1) == 0)) {
      const ulonglong2* q = (const ulonglong2*)p;
#pragma unroll
      for (int k = 0; k < VE / 2; ++k) {
        ulonglong2 v = q[k];
        d[2 * k] = (int)(unsigned)v.x; d[2 * k + 1] = (int)(unsigned)v.y;
      }
    } else {
      for (int k = 0; k < n; ++k) d[k] = (int)(unsigned)p[k];
    }
  } else {
    const int* p = (const int*)ei + E + base;
    if (n == VE && (((E + base) & 3) == 0)) {
      const int4* q = (const int4*)p;
#pragma unroll
      for (int k = 0; k < VE / 4; ++k) {
        int4 v = q[k];
        d[4 * k] = v.x; d[4 * k + 1] = v.y; d[4 * k + 2] = v.z; d[4 * k + 3] = v.w;
      }
    } else {
      for (int k = 0; k < n; ++k) d[k] = p[k];
    }
  }
  return n;
}

// load up to VE dst values from the compacted int32 array (scans 2-4)
__device__ __forceinline__ int load_dsts32(const int* dst32, long long E,
                                           long long base, int d[VE]) {
  int n = (int)((E - base) < VE ? (E - base) : VE);
  if (n == VE) {  // base is a multiple of VE -> 16B aligned
    int4 a = ((const int4*)(dst32 + base))[0];
    int4 b = ((const int4*)(dst32 + base))[1];
    d[0] = a.x; d[1] = a.y; d[2] = a.z; d[3] = a.w;
    d[4] = b.x; d[5] = b.y; d[6] = b.z; d[7] = b.w;
  } else {
    for (int k = 0; k < n; ++k) d[k] = dst32[base + k];
  }
  return n;
}

// F1 discovery (dst == n0, bm2+node2) + n0 seed + dst32 compaction + l3 list
// + grid-stride zeroing of deg/slot1/rc1/rc2 (zbig, int4 stores).
__global__ void k_scanF1(const void* ei, int E, const int* nidx_p, int* dst32,
                         unsigned* bm2, int* node2, int* cnt2, int* l3, int* ec3,
                         int4* zbig, int zi4) {
  int gid = blockIdx.x * TPB + threadIdx.x;
  for (int i = gid; i < zi4; i += gridDim.x * TPB)
    zbig[i] = make_int4(0, 0, 0, 0);
  int is64 = detect64(ei);
  int nidx = *nidx_p;
  if (gid == 0) {  // seed n0 into F1
    if (bmSet(bm2, nidx)) {
      int p = atomicAdd(cnt2, 1) & (CAP2 - 1);
      node2[p] = nidx;
    }
  }
  long long base = (long long)gid * VE;
  if (base >= E) return;
  int d[VE];
  int n = load_dsts(ei, E, base, is64, d);
  if (n == VE) {
    ((int4*)(dst32 + base))[0] = make_int4(d[0], d[1], d[2], d[3]);
    ((int4*)(dst32 + base))[1] = make_int4(d[4], d[5], d[6], d[7]);
  } else {
    for (int k = 0; k < n; ++k) dst32[base + k] = d[k];
  }
  for (int k = 0; k < n; ++k) {
    if (d[k] == nidx) {
      int s = ld_src(ei, is64, base + k);
      if (bmSet(bm2, s)) {
        int p = atomicAdd(cnt2, 1) & (CAP2 - 1);
        node2[p] = s;
      }
      int q = atomicAdd(ec3, 1);
      if (q < CL3) l3[q] = s;
    }
  }
}

// F2 discovery: prologue propagates F1 -> slot1/bm1/bmN; main loop tests the
// L1-hot bm2 bitmap; hits (~280) do the slow-path row search + claims.
__global__ void k_scanF2(const void* ei, int E, const int* dst32,
                         const unsigned* bm2, const int* node2, const int* cnt2,
                         unsigned* bm1, unsigned* bmN,
                         int* slot1, int* node1, int* cnt1,
                         int* rc2, int* bl2) {
  int rows2 = min(*cnt2, CAP2);
  for (int r = threadIdx.x; r < rows2; r += TPB) {
    int i = node2[r];
    bmSet(bmN, i);
    bmSet(bm1, i);
    if (atomicCAS(&slot1[i], 0, -1) == 0) {
      int p = atomicAdd(cnt1, 1) & (CAP1 - 1);
      slot1[i] = p + 1; node1[p] = i;
    }
  }
  int is64 = detect64(ei);
  long long base = ((long long)blockIdx.x * TPB + threadIdx.x) * VE;
  if (base >= E) return;
  int d[VE];
  int n = load_dsts32(dst32, E, base, d);
  for (int k = 0; k < n; ++k) {
    if (bmTest(bm2, d[k])) {
      int ad = 0;  // F1 row of d[k]: linear search (rows2 ~ 17, L1-hot)
      for (int r = 0; r < rows2; ++r)
        if (node2[r] == d[k]) { ad = r; break; }
      int s = ld_src(ei, is64, base + k);
      bmSet(bmN, s);
      bmSet(bm1, s);
      if (atomicCAS(&slot1[s], 0, -1) == 0) {
        int p = atomicAdd(cnt1, 1) & (CAP1 - 1);
        slot1[s] = p + 1; node1[p] = s;
      }
      int q = atomicAdd(&rc2[ad], 1);
      if (q < RB2) bl2[ad * RB2 + q] = s;
    }
  }
}

// S marking + layer-1 buckets: bm1 bitmap test; hits (~4.6K) read slot1.
__global__ void k_scanS(const void* ei, int E, const int* dst32,
                        const unsigned* bm1, const int* slot1, unsigned* bmN,
                        int* rc1, int* bl1) {
  int is64 = detect64(ei);
  long long base = ((long long)blockIdx.x * TPB + threadIdx.x) * VE;
  if (base >= E) return;
  int d[VE];
  int n = load_dsts32(dst32, E, base, d);
  for (int k = 0; k < n; ++k) {
    if (bmTest(bm1, d[k])) {
      int ad = slot1[d[k]] - 1;
      int s = ld_src(ei, is64, base + k);
      bmSet(bmN, s);
      int q = atomicAdd(&rc1[ad], 1);
      if (q < RB1) bl1[ad * RB1 + q] = s;
    }
  }
}

// degree histogram filtered by the bmN bitmap (~80K atomics on hits)
__global__ void k_scanDeg(int E, const int* dst32, const unsigned* bmN,
                          int* deg) {
  long long base = ((long long)blockIdx.x * TPB + threadIdx.x) * VE;
  if (base >= E) return;
  int d[VE];
  int n = load_dsts32(dst32, E, base, d);
  for (int k = 0; k < n; ++k)
    if (bmTest(bmN, d[k])) atomicAdd(&deg[d[k]], 1);
}

// layer 1, one wave per F2 row (factorized: neighbor-sum then one matvec).
__global__ void k_l1(const float* __restrict__ x, const float* __restrict__ W1,
                     const float* __restrict__ b1, const int* __restrict__ deg,
                     const int* __restrict__ node1, const int* __restrict__ cnt1,
                     const int* __restrict__ rc1, const int* __restrict__ bl1,
                     float* __restrict__ h1c) {
  int w = blockIdx.x * 4 + (threadIdx.x >> 6);
  int lane = threadIdx.x & 63;
  int rows = min(*cnt1, CAP1);
  if (w >= rows) return;
  int i = node1[w];
  float di = 1.0f / sqrtf((float)(deg[i] + 1));
  int cnt = min(rc1[w], RB1);
  float ax = 0.f, ay = 0.f, az = 0.f, aw = 0.f;
  for (int j = lane; j < cnt; j += 64) {
    int s = bl1[w * RB1 + j];
    float c = (1.0f / sqrtf((float)(deg[s] + 1))) * di;
    float4 xv = ((const float4*)x)[s];
    ax += c * xv.x; ay += c * xv.y; az += c * xv.z; aw += c * xv.w;
  }
#pragma unroll
  for (int t = 1; t < 64; t <<= 1) {
    ax += __shfl_xor(ax, t); ay += __shfl_xor(ay, t);
    az += __shfl_xor(az, t); aw += __shfl_xor(aw, t);
  }
  float4 xi = ((const float4*)x)[i];
  float dd = di * di;
  ax += dd * xi.x; ay += dd * xi.y; az += dd * xi.z; aw += dd * xi.w;
  float v = ax * W1[lane] + ay * W1[64 + lane] + az * W1[128 + lane] +
            aw * W1[192 + lane] + b1[lane];
  h1c[w * HID + lane] = v > 0.f ? v : 0.f;
}

// fused layer-2 + layer-3 + head. ONE block, 16 waves, batched gathers,
// loop-guards only (every thread reaches every barrier).
__global__ __launch_bounds__(TT) void k_l2tail(
    const float* __restrict__ W2, const float* __restrict__ b2,
    const int* __restrict__ deg, const int* __restrict__ node2,
    const int* __restrict__ cnt2, const int* __restrict__ slot1,
    const int* __restrict__ rc2, const int* __restrict__ bl2,
    const float* __restrict__ h1c, float* __restrict__ h2c,
    const int* __restrict__ nidx_p,
    const int* __restrict__ l3, const int* __restrict__ ec3,
    const float* __restrict__ W3, const float* __restrict__ b3,
    const float* __restrict__ Wp, const float* __restrict__ bp,
    const float* __restrict__ Wa, const float* __restrict__ ba,
    const float* __restrict__ Wm, const float* __restrict__ bm,
    const float* __restrict__ Wg, const float* __restrict__ bg,
    const float* __restrict__ Wt, const float* __restrict__ bt,
    float* __restrict__ out) {
  __shared__ float h2s[64][HID];   // F1 h2 rows (spill to h2c >= 64)
  __shared__ float sh[NW][HID];    // per-wave row buffer for W2 matvec
  __shared__ float part[NW][HID];  // cross-wave reduce buffer
  __shared__ float g3[HID];
  __shared__ float h3[HID];
  __shared__ float p[HID];
  __shared__ int   ssl[64];
  __shared__ float scc[64];
  __shared__ int   sn2[CAP2];      // node2 copy for row search
  int tid = threadIdx.x, wv = tid >> 6, lane = tid & 63;
  int nidx = *nidx_p;
  int rows = min(*cnt2, CAP2);
  for (int r = tid; r < rows; r += TT) sn2[r] = node2[r];
  __syncthreads();

  // ---- phase A: layer 2, one wave per F1 row ----
  for (int w = wv; w < rows; w += NW) {
    int i = sn2[w];
    float di = 1.0f / sqrtf((float)(deg[i] + 1));
    int cnt = min(rc2[w], RB2);
    float acc = 0.f;
    for (int j0 = 0; j0 < cnt; j0 += 64) {
      int nb = min(64, cnt - j0);
      int sl = 0; float c = 0.f;
      if (lane < nb) {
        int s = bl2[w * RB2 + j0 + lane];
        sl = slot1[s] - 1;
        c = (1.0f / sqrtf((float)(deg[s] + 1))) * di;
      }
      int j = 0;
      for (; j + 8 <= nb; j += 8) {
        int r0 = __shfl(sl, j + 0), r1 = __shfl(sl, j + 1);
        int r2 = __shfl(sl, j + 2), r3 = __shfl(sl, j + 3);
        int r4 = __shfl(sl, j + 4), r5 = __shfl(sl, j + 5);
        int r6 = __shfl(sl, j + 6), r7 = __shfl(sl, j + 7);
        float v0 = h1c[r0 * HID + lane];
        float v1 = h1c[r1 * HID + lane];
        float v2 = h1c[r2 * HID + lane];
        float v3 = h1c[r3 * HID + lane];
        float v4 = h1c[r4 * HID + lane];
        float v5 = h1c[r5 * HID + lane];
        float v6 = h1c[r6 * HID + lane];
        float v7 = h1c[r7 * HID + lane];
        acc += __shfl(c, j + 0) * v0 + __shfl(c, j + 1) * v1 +
               __shfl(c, j + 2) * v2 + __shfl(c, j + 3) * v3 +
               __shfl(c, j + 4) * v4 + __shfl(c, j + 5) * v5 +
               __shfl(c, j + 6) * v6 + __shfl(c, j + 7) * v7;
      }
      for (; j < nb; ++j)
        acc += __shfl(c, j) * h1c[__shfl(sl, j) * HID + lane];
    }
    acc += di * di * h1c[(slot1[i] - 1) * HID + lane];
    sh[wv][lane] = acc;  // same-wave write->read (lockstep)
    float v = b2[lane];
#pragma unroll 16
    for (int k = 0; k < HID; ++k) v += sh[wv][k] * W2[k * HID + lane];
    v = v > 0.f ? v : 0.f;
    if (w < 64) h2s[w][lane] = v; else h2c[w * HID + lane] = v;
  }
  __syncthreads();

  // ---- phase B: layer-3 aggregate over l3 list (batched), 16 waves ----
  float dn = 1.0f / sqrtf((float)(deg[nidx] + 1));
  int cnt = min(*ec3, CL3);
  float acc = 0.f;
  for (int j0 = 0; j0 < cnt; j0 += 64) {
    int nb = min(64, cnt - j0);
    if (tid < nb) {
      int s = l3[j0 + tid];
      int r = 0;  // F1 row of s: linear search (rows ~ 17, LDS)
      for (int u = 0; u < rows; ++u)
        if (sn2[u] == s) { r = u; break; }
      ssl[tid] = r;
      scc[tid] = (1.0f / sqrtf((float)(deg[s] + 1))) * dn;
    }
    __syncthreads();
    int j = wv;
    for (; j + 48 < nb; j += 64) {  // 4 batched rows per wave
      int r0 = ssl[j], r1 = ssl[j + 16], r2 = ssl[j + 32], r3 = ssl[j + 48];
      float v0 = (r0 < 64) ? h2s[r0][lane] : h2c[r0 * HID + lane];
      float v1 = (r1 < 64) ? h2s[r1][lane] : h2c[r1 * HID + lane];
      float v2 = (r2 < 64) ? h2s[r2][lane] : h2c[r2 * HID + lane];
      float v3 = (r3 < 64) ? h2s[r3][lane] : h2c[r3 * HID + lane];
      acc += scc[j] * v0 + scc[j + 16] * v1 + scc[j + 32] * v2 +
             scc[j + 48] * v3;
    }
    for (; j < nb; j += NW) {
      int r = ssl[j];
      float hv = (r < 64) ? h2s[r][lane] : h2c[r * HID + lane];
      acc += scc[j] * hv;
    }
    __syncthreads();
  }
  part[wv][lane] = acc;
  __syncthreads();
  if (wv == 0) {
    float a = 0.f;
#pragma unroll
    for (int u = 0; u < NW; ++u) a += part[u][lane];
    int r = 0;
    for (int u = 0; u < rows; ++u)
      if (sn2[u] == nidx) { r = u; break; }
    float hv = (r < 64) ? h2s[r][lane] : h2c[r * HID + lane];
    g3[lane] = a + dn * dn * hv;
  }
  __syncthreads();
  {  // h3 = relu(g3 @ W3 + b3), k-split over 16 waves (4 k each)
    int k0 = wv * 4;
    float v = g3[k0] * W3[k0 * HID + lane] +
              g3[k0 + 1] * W3[(k0 + 1) * HID + lane] +
              g3[k0 + 2] * W3[(k0 + 2) * HID + lane] +
              g3[k0 + 3] * W3[(k0 + 3) * HID + lane];
    part[wv][lane] = v;
  }
  __syncthreads();
  if (wv == 0) {
    float v = b3[lane];
#pragma unroll
    for (int u = 0; u < NW; ++u) v += part[u][lane];
    h3[lane] = v > 0.f ? v : 0.f;
  }
  __syncthreads();
  {  // p = relu(h3 @ Wp + bp), k-split over 16 waves
    int k0 = wv * 4;
    float v = h3[k0] * Wp[k0 * HID + lane] +
              h3[k0 + 1] * Wp[(k0 + 1) * HID + lane] +
              h3[k0 + 2] * Wp[(k0 + 2) * HID + lane] +
              h3[k0 + 3] * Wp[(k0 + 3) * HID + lane];
    part[wv][lane] = v;
  }
  __syncthreads();
  if (wv == 0) {
    float v = bp[lane];
#pragma unroll
    for (int u = 0; u < NW; ++u) v += part[u][lane];
    p[lane] = v > 0.f ? v : 0.f;
  }
  __syncthreads();
  if (tid < 4) {
    float o = ba[tid];
#pragma unroll 8
    for (int k = 0; k < HID; ++k) o += p[k] * Wa[k * 4 + tid];
    out[tid] = o;
  } else if (tid < 6) {
    int c = tid - 4; float o = bm[c];
#pragma unroll 8
    for (int k = 0; k < HID; ++k) o += p[k] * Wm[k * 2 + c];
    out[tid] = o;
  } else if (tid < 9) {
    int c = tid - 6; float o = bg[c];
#pragma unroll 8
    for (int k = 0; k < HID; ++k) o += p[k] * Wg[k * 3 + c];
    out[tid] = o;
  } else if (tid < 19) {
    int c = tid - 9; float o = bt[c];
#pragma unroll 8
    for (int k = 0; k < HID; ++k) o += p[k] * Wt[k * 10 + c];
    out[tid] = o;
  }
}

extern "C" void kernel_launch(void* const* d_in, const int* in_sizes, int n_in,
                              void* d_out, int out_size, void* d_ws, size_t ws_size,
                              hipStream_t stream) {
  const float* x  = (const float*)d_in[0];
  const void*  ei = d_in[1];
  const int* nidx = (const int*)d_in[2];
  const float* W1 = (const float*)d_in[3];
  const float* b1 = (const float*)d_in[4];
  const float* W2 = (const float*)d_in[5];
  const float* b2 = (const float*)d_in[6];
  const float* W3 = (const float*)d_in[7];
  const float* b3 = (const float*)d_in[8];
  const float* Wp = (const float*)d_in[9];
  const float* bp = (const float*)d_in[10];
  const float* Wa = (const float*)d_in[11];
  const float* ba = (const float*)d_in[12];
  const float* Wm = (const float*)d_in[13];
  const float* bm = (const float*)d_in[14];
  const float* Wg = (const float*)d_in[15];
  const float* bg = (const float*)d_in[16];
  const float* Wt = (const float*)d_in[17];
  const float* bt = (const float*)d_in[18];
  float* out = (float*)d_out;

  int N = in_sizes[0] / 4;   // 100000
  int E = in_sizes[1] / 2;   // 1600000

  char* w = (char*)d_ws;
  size_t o = 0;
  auto take = [&](size_t bytes) -> void* {
    void* p = w + o;
    o += (bytes + 255) & ~(size_t)255;
    return p;
  };
  // small zero region (ONE memset, 38KB): counters + 3 bitmaps
  size_t zeroInts = 16 + 3 * BMW;
  int* zr = (int*)take(zeroInts * 4);
  int*      cnt1 = zr + 0;
  int*      cnt2 = zr + 1;
  int*      ec3  = zr + 2;
  unsigned* bm2  = (unsigned*)(zr + 16);        // F1 membership
  unsigned* bm1  = bm2 + BMW;                   // F2 membership
  unsigned* bmN  = bm1 + BMW;                   // need (degree targets)
  // big region zeroed grid-stride inside scanF1: deg, slot1, rc1, rc2
  int zbigInts = 2 * N + CAP1 + CAP2;
  int* zbig  = (int*)take((size_t)zbigInts * 4);
  int* deg   = zbig;
  int* slot1 = deg + N;
  int* rc1   = slot1 + N;
  int* rc2   = rc1 + CAP1;
  int*   dst32 = (int*)take((size_t)E * 4);
  int*   node1 = (int*)take((size_t)CAP1 * 4);
  int*   node2 = (int*)take((size_t)CAP2 * 4);
  int*   bl1   = (int*)take((size_t)CAP1 * RB1 * 4);
  int*   bl2   = (int*)take((size_t)CAP2 * RB2 * 4);
  int*   l3    = (int*)take((size_t)CL3 * 4);
  float* h1c   = (float*)take((size_t)CAP1 * HID * 4);
  float* h2c   = (float*)take((size_t)CAP2 * HID * 4);

  int gS = (int)(((long long)E + TPB * VE - 1) / (TPB * VE));
  int zi4 = zbigInts / 4;  // int4 count (zbigInts is a multiple of 4)

  hipMemsetAsync(zr, 0x00, zeroInts * 4, stream);
  k_scanF1 <<<gS, TPB, 0, stream>>>(ei, E, nidx, dst32, bm2, node2, cnt2,
                                    l3, ec3, (int4*)zbig, zi4);
  k_scanF2 <<<gS, TPB, 0, stream>>>(ei, E, dst32, bm2, node2, cnt2,
                                    bm1, bmN, slot1, node1, cnt1, rc2, bl2);
  k_scanS  <<<gS, TPB, 0, stream>>>(ei, E, dst32, bm1, slot1, bmN, rc1, bl1);
  k_scanDeg<<<gS, TPB, 0, stream>>>(E, dst32, bmN, deg);
  k_l1     <<<CAP1 / 4, TPB, 0, stream>>>(x, W1, b1, deg, node1, cnt1, rc1, bl1, h1c);
  k_l2tail <<<1, TT, 0, stream>>>(W2, b2, deg, node2, cnt2, slot1, rc2, bl2,
                                  h1c, h2c, nidx, l3, ec3, W3, b3,
                                  Wp, bp, Wa, ba, Wm, bm, Wg, bg, Wt, bt, out);
}